// Round 1
// baseline (1997.032 us; speedup 1.0000x reference)
//
#include <hip/hip_runtime.h>
#include <cstdint>
#include <cstddef>

// ---------------------------------------------------------------------------
// LTIModel: x_{t+1} = x_t M + y_t P (exact RK4 polynomial), u_t = x_t Cu + y_t Duy
// B=32, T=2048, OBS=128, N=256, OUT=32, H=64, dt=0.01
// Decomposition: 64 chunks of 32 steps; local scans -> Kogge-Stone over chunks
// -> emission pass. Value MLP independent.
// ---------------------------------------------------------------------------

static constexpr float H_DT = 0.01f;

// ws layout (floats)
static constexpr size_t OFF_A2 = 0;        // 65536
static constexpr size_t OFF_A3 = 65536;    // 65536
static constexpr size_t OFF_A4 = 131072;   // 65536
static constexpr size_t OFF_PI = 196608;   // 65536  (Pinner)
static constexpr size_t OFF_P  = 262144;   // 32768  (P: [128][256])
static constexpr size_t OFF_MP = 294912;   // 11*65536 (Mpows[p] = M^(2^p), p=0..10)
static constexpr size_t OFF_SA = 1015808;  // 65*8192
static constexpr size_t OFF_SB = 1548288;  // 65*8192
static constexpr size_t WS_FLOATS = 2080768;

// out layout (floats)
static constexpr size_t OUT_XF  = 4194304; // 32*2048*64
static constexpr size_t OUT_VAL = 4202496; // + 32*256

// ---------------------------------------------------------------------------
// Generic small matmul: C[M x N] = alpha * A[M x K] @ B[K x N], row-major.
// Tiles 32x32, K multiple of 32. grid = (N/32, M/32), block = 256.
// ---------------------------------------------------------------------------
__global__ void __launch_bounds__(256) mm_kernel(const float* __restrict__ A,
                                                 const float* __restrict__ B,
                                                 float* __restrict__ C,
                                                 int Mm, int K, int Nn, float alpha)
{
  __shared__ float As[32][33];
  __shared__ float Bs[32][33];
  const int bx = blockIdx.x, by = blockIdx.y;
  const int tx = threadIdx.x & 31, ty = threadIdx.x >> 5; // ty 0..7
  float acc[4] = {0.f, 0.f, 0.f, 0.f};
  for (int k0 = 0; k0 < K; k0 += 32) {
    #pragma unroll
    for (int i = 0; i < 4; i++) {
      As[ty * 4 + i][tx] = A[(size_t)(by * 32 + ty * 4 + i) * K + k0 + tx];
      Bs[ty * 4 + i][tx] = B[(size_t)(k0 + ty * 4 + i) * Nn + bx * 32 + tx];
    }
    __syncthreads();
    #pragma unroll
    for (int k = 0; k < 32; k++) {
      const float bv = Bs[k][tx];
      #pragma unroll
      for (int i = 0; i < 4; i++) acc[i] += As[ty * 4 + i][k] * bv;
    }
    __syncthreads();
  }
  #pragma unroll
  for (int i = 0; i < 4; i++)
    C[(size_t)(by * 32 + ty * 4 + i) * Nn + bx * 32 + tx] = alpha * acc[i];
}

// D = I + c1*A1 + c2*A2 + c3*A3 + c4*A4   (256x256), grid 256 x 256 threads
__global__ void __launch_bounds__(256) ewpoly_kernel(float* __restrict__ D,
                                                     const float* __restrict__ A1,
                                                     const float* __restrict__ A2,
                                                     const float* __restrict__ A3,
                                                     const float* __restrict__ A4,
                                                     float c1, float c2, float c3, float c4)
{
  const int i = blockIdx.x * 256 + threadIdx.x;
  const int r = i >> 8, c = i & 255;
  float v = (r == c) ? 1.0f : 0.0f;
  v += c1 * A1[i] + c2 * A2[i] + c3 * A3[i] + c4 * A4[i];
  D[i] = v;
}

__global__ void __launch_bounds__(256) copy_kernel(float* __restrict__ dst,
                                                   const float* __restrict__ src, int n)
{
  const int i = blockIdx.x * 256 + threadIdx.x;
  if (i < n) dst[i] = src[i];
}

// stage obs rows (bg*8 .. bg*8+7) at time t into obsL[8][128]
__device__ __forceinline__ void stage_obs(float (*obsL)[128], const float* __restrict__ obs,
                                          int bg, int t)
{
  const int b  = threadIdx.x >> 5;  // 0..7
  const int o4 = threadIdx.x & 31;  // 0..31
  const float4 v = *reinterpret_cast<const float4*>(
      obs + ((size_t)(bg * 8 + b) * 2048 + (size_t)t) * 128 + o4 * 4);
  *reinterpret_cast<float4*>(&obsL[b][o4 * 4]) = v;
}

// ---------------------------------------------------------------------------
// K2a: per-chunk local scan from zero -> d_j written to Sa[1+j].
// grid (64 chunks, 4 batch-groups), block 256 (thread = output column n).
// ---------------------------------------------------------------------------
__global__ void __launch_bounds__(256) local_scan_kernel(const float* __restrict__ obs,
                                                         const float* __restrict__ Pm,
                                                         const float* __restrict__ Mm,
                                                         float* __restrict__ Sa)
{
  __shared__ float xL[8][256];
  __shared__ float obsL[8][128];
  const int j = blockIdx.x, bg = blockIdx.y;
  const int n = threadIdx.x;
  const int t0 = j * 32;
  stage_obs(obsL, obs, bg, t0);
  __syncthreads();
  float acc[8];
  #pragma unroll 1
  for (int dd = 0; dd < 32; dd++) {
    #pragma unroll
    for (int b = 0; b < 8; b++) acc[b] = 0.f;
    // c part: acc[b] += sum_o obsL[b][o] * P[o][n]
    #pragma unroll 4
    for (int oq = 0; oq < 128; oq += 4) {
      const float* pp = Pm + (size_t)oq * 256 + n;
      const float p0 = pp[0], p1 = pp[256], p2 = pp[512], p3 = pp[768];
      #pragma unroll
      for (int b = 0; b < 8; b++) {
        const float4 yv = *reinterpret_cast<const float4*>(&obsL[b][oq]);
        acc[b] += yv.x * p0 + yv.y * p1 + yv.z * p2 + yv.w * p3;
      }
    }
    if (dd > 0) {
      #pragma unroll 4
      for (int mq = 0; mq < 256; mq += 4) {
        const float* mp = Mm + (size_t)mq * 256 + n;
        const float m0 = mp[0], m1 = mp[256], m2 = mp[512], m3 = mp[768];
        #pragma unroll
        for (int b = 0; b < 8; b++) {
          const float4 xv = *reinterpret_cast<const float4*>(&xL[b][mq]);
          acc[b] += xv.x * m0 + xv.y * m1 + xv.z * m2 + xv.w * m3;
        }
      }
    }
    __syncthreads();
    #pragma unroll
    for (int b = 0; b < 8; b++) xL[b][n] = acc[b];
    if (dd < 31) stage_obs(obsL, obs, bg, t0 + dd + 1);
    __syncthreads();
  }
  float* dst = Sa + (size_t)(1 + j) * 8192 + (size_t)bg * 2048;
  #pragma unroll
  for (int b = 0; b < 8; b++) dst[b * 256 + n] = acc[b];
}

// ---------------------------------------------------------------------------
// Kogge-Stone round: out[j] = in[j] + (j>=s ? in[j-s] @ W : 0), elements [32][256]
// grid (64, 4), block 256. W = M^(32*s).
// ---------------------------------------------------------------------------
__global__ void __launch_bounds__(256) scan_round_kernel(const float* __restrict__ in,
                                                         float* __restrict__ out,
                                                         const float* __restrict__ W, int s)
{
  const int j = blockIdx.x, bg = blockIdx.y;
  const int n = threadIdx.x;
  const size_t eoff = (size_t)j * 8192 + (size_t)bg * 2048;
  if (j < s) {
    #pragma unroll
    for (int b = 0; b < 8; b++) out[eoff + b * 256 + n] = in[eoff + b * 256 + n];
    return;
  }
  __shared__ float xL[8][256];
  const size_t soff = (size_t)(j - s) * 8192 + (size_t)bg * 2048;
  #pragma unroll
  for (int b = 0; b < 8; b++) xL[b][n] = in[soff + b * 256 + n];
  __syncthreads();
  float acc[8];
  #pragma unroll
  for (int b = 0; b < 8; b++) acc[b] = in[eoff + b * 256 + n];
  #pragma unroll 4
  for (int mq = 0; mq < 256; mq += 4) {
    const float* wp = W + (size_t)mq * 256 + n;
    const float w0 = wp[0], w1 = wp[256], w2 = wp[512], w3 = wp[768];
    #pragma unroll
    for (int b = 0; b < 8; b++) {
      const float4 xv = *reinterpret_cast<const float4*>(&xL[b][mq]);
      acc[b] += xv.x * w0 + xv.y * w1 + xv.z * w2 + xv.w * w3;
    }
  }
  #pragma unroll
  for (int b = 0; b < 8; b++) out[eoff + b * 256 + n] = acc[b];
}

// ---------------------------------------------------------------------------
// K2b: emission pass. Re-run chunk from s_j; per step write u and log_stds;
// chunk 63 also writes x_final. grid (64, 4), block 256.
// ---------------------------------------------------------------------------
__global__ void __launch_bounds__(256) emit_kernel(const float* __restrict__ obs,
                                                   const float* __restrict__ Pm,
                                                   const float* __restrict__ Mm,
                                                   const float* __restrict__ S,
                                                   const float* __restrict__ Cu,
                                                   const float* __restrict__ Duy,
                                                   const float* __restrict__ logstd,
                                                   float* __restrict__ out)
{
  __shared__ float xL[8][256];
  __shared__ float obsL[8][128];
  const int j = blockIdx.x, bg = blockIdx.y;
  const int n = threadIdx.x;
  const int t0 = j * 32;
  {
    const float* sp = S + (size_t)j * 8192 + (size_t)bg * 2048;
    #pragma unroll
    for (int b = 0; b < 8; b++) xL[b][n] = sp[b * 256 + n];
  }
  stage_obs(obsL, obs, bg, t0);
  __syncthreads();
  const int ob = n >> 5, oo = n & 31;
  const float ls = logstd[oo];
  const size_t orow0 = (size_t)(bg * 8 + ob) * 2048 * 64;
  float acc[8];
  #pragma unroll 1
  for (int dd = 0; dd < 32; dd++) {
    const int t = t0 + dd;
    // u = x_t @ Cu + y_t @ Duy   (thread handles batch ob, output oo)
    float u = 0.f;
    #pragma unroll 4
    for (int mq = 0; mq < 256; mq += 4) {
      const float* cp = Cu + (size_t)mq * 32 + oo;
      const float c0 = cp[0], c1 = cp[32], c2 = cp[64], c3 = cp[96];
      const float4 xv = *reinterpret_cast<const float4*>(&xL[ob][mq]);
      u += xv.x * c0 + xv.y * c1 + xv.z * c2 + xv.w * c3;
    }
    #pragma unroll 4
    for (int oq = 0; oq < 128; oq += 4) {
      const float* dp = Duy + (size_t)oq * 32 + oo;
      const float d0 = dp[0], d1 = dp[32], d2 = dp[64], d3 = dp[96];
      const float4 yv = *reinterpret_cast<const float4*>(&obsL[ob][oq]);
      u += yv.x * d0 + yv.y * d1 + yv.z * d2 + yv.w * d3;
    }
    {
      float* op = out + orow0 + (size_t)t * 64;
      op[oo] = u;
      op[32 + oo] = ls;
    }
    // state update: x <- x @ M + y @ P
    #pragma unroll
    for (int b = 0; b < 8; b++) acc[b] = 0.f;
    #pragma unroll 4
    for (int oq = 0; oq < 128; oq += 4) {
      const float* pp = Pm + (size_t)oq * 256 + n;
      const float p0 = pp[0], p1 = pp[256], p2 = pp[512], p3 = pp[768];
      #pragma unroll
      for (int b = 0; b < 8; b++) {
        const float4 yv = *reinterpret_cast<const float4*>(&obsL[b][oq]);
        acc[b] += yv.x * p0 + yv.y * p1 + yv.z * p2 + yv.w * p3;
      }
    }
    #pragma unroll 4
    for (int mq = 0; mq < 256; mq += 4) {
      const float* mp = Mm + (size_t)mq * 256 + n;
      const float m0 = mp[0], m1 = mp[256], m2 = mp[512], m3 = mp[768];
      #pragma unroll
      for (int b = 0; b < 8; b++) {
        const float4 xv = *reinterpret_cast<const float4*>(&xL[b][mq]);
        acc[b] += xv.x * m0 + xv.y * m1 + xv.z * m2 + xv.w * m3;
      }
    }
    __syncthreads();
    #pragma unroll
    for (int b = 0; b < 8; b++) xL[b][n] = acc[b];
    if (dd < 31) stage_obs(obsL, obs, bg, t0 + dd + 1);
    __syncthreads();
  }
  if (j == 63) {
    float* xf = out + OUT_XF + (size_t)bg * 2048;
    #pragma unroll
    for (int b = 0; b < 8; b++) xf[b * 256 + n] = acc[b];
  }
}

// ---------------------------------------------------------------------------
// Value MLP: thread-per-row, 64 rows per WG staged in padded LDS.
// grid 1024, block 64.
// ---------------------------------------------------------------------------
__global__ void __launch_bounds__(64) mlp_kernel(const float* __restrict__ obs,
                                                 const float* __restrict__ W0,
                                                 const float* __restrict__ b0,
                                                 const float* __restrict__ W1,
                                                 const float* __restrict__ b1,
                                                 const float* __restrict__ W2,
                                                 const float* __restrict__ b2,
                                                 float* __restrict__ val)
{
  __shared__ float oL[64][129];
  const int wg = blockIdx.x;
  const size_t base = (size_t)wg * 64 * 128;
  #pragma unroll 4
  for (int i = 0; i < 32; i++) {
    const int idx = i * 64 + threadIdx.x;  // float4 index
    const float4 v = *reinterpret_cast<const float4*>(obs + base + (size_t)idx * 4);
    const int r = idx >> 5, c4 = idx & 31;
    oL[r][c4 * 4 + 0] = v.x;
    oL[r][c4 * 4 + 1] = v.y;
    oL[r][c4 * 4 + 2] = v.z;
    oL[r][c4 * 4 + 3] = v.w;
  }
  __syncthreads();
  const int r = threadIdx.x;
  float h0[64];
  #pragma unroll
  for (int jj = 0; jj < 64; jj++) h0[jj] = b0[jj];
  #pragma unroll 2
  for (int k = 0; k < 128; k++) {
    const float x = oL[r][k];
    const float* w = W0 + (size_t)k * 64;
    #pragma unroll
    for (int jj = 0; jj < 64; jj++) h0[jj] += x * w[jj];
  }
  #pragma unroll
  for (int jj = 0; jj < 64; jj++) h0[jj] = tanhf(h0[jj]);
  float h1[64];
  #pragma unroll
  for (int jj = 0; jj < 64; jj++) h1[jj] = b1[jj];
  #pragma unroll 2
  for (int k = 0; k < 64; k++) {
    const float x = h0[k];
    const float* w = W1 + (size_t)k * 64;
    #pragma unroll
    for (int jj = 0; jj < 64; jj++) h1[jj] += x * w[jj];
  }
  float v = b2[0];
  #pragma unroll
  for (int jj = 0; jj < 64; jj++) v += tanhf(h1[jj]) * W2[jj];
  val[(size_t)wg * 64 + r] = v;
}

// ---------------------------------------------------------------------------
extern "C" void kernel_launch(void* const* d_in, const int* in_sizes, int n_in,
                              void* d_out, int out_size, void* d_ws, size_t ws_size,
                              hipStream_t stream)
{
  (void)in_sizes; (void)n_in; (void)out_size;
  if (ws_size < WS_FLOATS * sizeof(float)) return;  // fail loudly (out stays poisoned)

  const float* obs  = (const float*)d_in[0];
  const float* x0   = (const float*)d_in[1];
  const float* A_T  = (const float*)d_in[2];
  const float* ByT  = (const float*)d_in[3];
  const float* CuT  = (const float*)d_in[4];
  const float* DuyT = (const float*)d_in[5];
  const float* lstd = (const float*)d_in[6];
  const float* W0   = (const float*)d_in[7];
  const float* b0   = (const float*)d_in[8];
  const float* W1   = (const float*)d_in[9];
  const float* b1   = (const float*)d_in[10];
  const float* W2   = (const float*)d_in[11];
  const float* b2   = (const float*)d_in[12];
  float* out = (float*)d_out;
  float* ws  = (float*)d_ws;

  float* A2 = ws + OFF_A2;
  float* A3 = ws + OFF_A3;
  float* A4 = ws + OFF_A4;
  float* Pi = ws + OFF_PI;
  float* P  = ws + OFF_P;
  float* Mp = ws + OFF_MP;   // Mp + p*65536 = M^(2^p)
  float* Sa = ws + OFF_SA;
  float* Sb = ws + OFF_SB;

  const float h = H_DT;

  // --- stage A: build M, P, and squarings ---
  mm_kernel<<<dim3(8, 8), 256, 0, stream>>>(A_T, A_T, A2, 256, 256, 256, 1.f);
  mm_kernel<<<dim3(8, 8), 256, 0, stream>>>(A2, A_T, A3, 256, 256, 256, 1.f);
  mm_kernel<<<dim3(8, 8), 256, 0, stream>>>(A2, A2, A4, 256, 256, 256, 1.f);
  // M = I + h A + h^2/2 A^2 + h^3/6 A^3 + h^4/24 A^4
  ewpoly_kernel<<<256, 256, 0, stream>>>(Mp, A_T, A2, A3, A4,
                                         h, h * h / 2.f, h * h * h / 6.f, h * h * h * h / 24.f);
  // Pinner = I + h/2 A + h^2/6 A^2 + h^3/24 A^3
  ewpoly_kernel<<<256, 256, 0, stream>>>(Pi, A_T, A2, A3, A4,
                                         h / 2.f, h * h / 6.f, h * h * h / 24.f, 0.f);
  // P = h * By_T @ Pinner
  mm_kernel<<<dim3(8, 4), 256, 0, stream>>>(ByT, Pi, P, 128, 256, 256, h);
  // squarings M^2 .. M^1024
  for (int p = 1; p <= 10; p++) {
    const float* src = Mp + (size_t)(p - 1) * 65536;
    mm_kernel<<<dim3(8, 8), 256, 0, stream>>>(src, src, Mp + (size_t)p * 65536, 256, 256, 256, 1.f);
  }

  // --- stage B ---
  copy_kernel<<<32, 256, 0, stream>>>(Sa, x0, 8192);  // Sa[0] = x0
  local_scan_kernel<<<dim3(64, 4), 256, 0, stream>>>(obs, P, Mp, Sa);  // Sa[1+j] = d_j

  // Kogge-Stone over 64 elements: shift 2^r uses W = M^(32*2^r) = Mp[5+r]
  float* cur = Sa;
  float* nxt = Sb;
  for (int r = 0; r < 6; r++) {
    scan_round_kernel<<<dim3(64, 4), 256, 0, stream>>>(cur, nxt, Mp + (size_t)(5 + r) * 65536, 1 << r);
    float* tmp = cur; cur = nxt; nxt = tmp;
  }
  // after 6 swaps, cur == Sa (holds s_j = state at chunk starts)

  emit_kernel<<<dim3(64, 4), 256, 0, stream>>>(obs, P, Mp, cur, CuT, DuyT, lstd, out);
  mlp_kernel<<<1024, 64, 0, stream>>>(obs, W0, b0, W1, b1, W2, b2, out + OUT_VAL);
}

// Round 2
// 1186.574 us; speedup vs baseline: 1.6830x; 1.6830x over previous
//
#include <hip/hip_runtime.h>
#include <cstdint>
#include <cstddef>

// ---------------------------------------------------------------------------
// LTIModel: x_{t+1} = x_t M + y_t P (exact RK4 polynomial),
//           u_t = x_t Cu + y_t Duy
// B=32, T=2048, OBS=128, N=256, OUT=32, H=64, dt=0.01
//
// Round-2 structure:
//   - scan_store: per (chunk j, batch-group bg of 4): 2-step fused local scan
//     from zero state; inline-emits z_t = x^loc_t-part of u; writes chunk
//     increment d_j.  grid (64,8) = 512 blocks = 2 blocks/CU.
//   - Kogge-Stone (6 rounds) over 64 chunk increments -> chunk-start states s_j.
//   - uhom_emit: one GEMM  [2048=j*32+b rows x 256] x Wstack[256 x 1024=tau*32+o],
//     epilogue adds z, writes actions + log_stds.
//   - xf: x_final = s_63 M^32 + d_63.   - mlp: value head.
// ---------------------------------------------------------------------------

static constexpr float H_DT = 0.01f;

// ws layout (floats)
static constexpr size_t OFF_A2   = 0;        // 65536
static constexpr size_t OFF_A3   = 65536;    // 65536
static constexpr size_t OFF_A4   = 131072;   // 65536
static constexpr size_t OFF_PI   = 196608;   // 65536
static constexpr size_t OFF_P    = 262144;   // 32768   P   [128][256]
static constexpr size_t OFF_PM   = 294912;   // 32768   P@M [128][256]
static constexpr size_t OFF_PCU  = 327680;   // 4096    P@Cu [128][32]
static constexpr size_t OFF_W    = 331776;   // 262144  Wstack [256][1024] (col tau*32+o = (M^tau Cu)[k][o])
static constexpr size_t OFF_TW0  = 593920;   // 8192    Cu^T   [32][256]
static constexpr size_t OFF_TW1  = 602112;   // 8192    (MCu)^T [32][256]
static constexpr size_t OFF_TPCU = 610304;   // 4096    (PCu)^T [32][128]
static constexpr size_t OFF_TDUY = 614400;   // 4096    Duy^T  [32][128]
static constexpr size_t OFF_MP   = 618496;   // 11*65536  Mp[p] = M^(2^p), p=0..10
static constexpr size_t OFF_SA   = 1339392;  // 65*8192
static constexpr size_t OFF_SB   = 1871872;  // 65*8192
static constexpr size_t OFF_Z    = 2404352;  // 2048*32*32  z[t][b][o]
static constexpr size_t WS_FLOATS = 4501504; // = OFF_Z + 2097152  (18.0 MB)

// out layout (floats)
static constexpr size_t OUT_XF  = 4194304; // 32*2048*64
static constexpr size_t OUT_VAL = 4202496; // + 32*256

// ---------------------------------------------------------------------------
// Generic small matmul: C[M x N] = alpha * A[M x K] @ B[K x N] with leading dims.
// Tiles 32x32, K multiple of 32. grid = (N/32, M/32), block = 256.
// ---------------------------------------------------------------------------
__global__ void __launch_bounds__(256) mm_kernel(const float* __restrict__ A,
                                                 const float* __restrict__ B,
                                                 float* __restrict__ C,
                                                 int K, int lda, int ldb, int ldc,
                                                 float alpha)
{
  __shared__ float As[32][33];
  __shared__ float Bs[32][33];
  const int bx = blockIdx.x, by = blockIdx.y;
  const int tx = threadIdx.x & 31, ty = threadIdx.x >> 5; // ty 0..7
  float acc[4] = {0.f, 0.f, 0.f, 0.f};
  for (int k0 = 0; k0 < K; k0 += 32) {
    #pragma unroll
    for (int i = 0; i < 4; i++) {
      As[ty * 4 + i][tx] = A[(size_t)(by * 32 + ty * 4 + i) * lda + k0 + tx];
      Bs[ty * 4 + i][tx] = B[(size_t)(k0 + ty * 4 + i) * ldb + bx * 32 + tx];
    }
    __syncthreads();
    #pragma unroll
    for (int k = 0; k < 32; k++) {
      const float bv = Bs[k][tx];
      #pragma unroll
      for (int i = 0; i < 4; i++) acc[i] += As[ty * 4 + i][k] * bv;
    }
    __syncthreads();
  }
  #pragma unroll
  for (int i = 0; i < 4; i++)
    C[(size_t)(by * 32 + ty * 4 + i) * ldc + bx * 32 + tx] = alpha * acc[i];
}

// D = I + c1*A1 + c2*A2 + c3*A3 + c4*A4   (256x256), grid 256 x 256 threads
__global__ void __launch_bounds__(256) ewpoly_kernel(float* __restrict__ D,
                                                     const float* __restrict__ A1,
                                                     const float* __restrict__ A2,
                                                     const float* __restrict__ A3,
                                                     const float* __restrict__ A4,
                                                     float c1, float c2, float c3, float c4)
{
  const int i = blockIdx.x * 256 + threadIdx.x;
  const int r = i >> 8, c = i & 255;
  float v = (r == c) ? 1.0f : 0.0f;
  v += c1 * A1[i] + c2 * A2[i] + c3 * A3[i] + c4 * A4[i];
  D[i] = v;
}

__global__ void __launch_bounds__(256) copy_kernel(float* __restrict__ dst,
                                                   const float* __restrict__ src, int n)
{
  const int i = blockIdx.x * 256 + threadIdx.x;
  if (i < n) dst[i] = src[i];
}

// Wstack[k][o] (ld 1024) = CuT[k][o] (ld 32).  grid 32 x 256.
__global__ void __launch_bounds__(256) copyW0_kernel(float* __restrict__ W,
                                                     const float* __restrict__ CuT)
{
  const int idx = blockIdx.x * 256 + threadIdx.x; // 0..8191
  W[(size_t)(idx >> 5) * 1024 + (idx & 31)] = CuT[idx];
}

// dst[c*R + r] = src[r*ld + c], C fixed at 32.  grid (R*32/256) x 256.
__global__ void __launch_bounds__(256) transpose32_kernel(const float* __restrict__ src,
                                                          float* __restrict__ dst,
                                                          int R, int ld)
{
  const int idx = blockIdx.x * 256 + threadIdx.x;
  const int r = idx >> 5, c = idx & 31;
  if (r < R) dst[(size_t)c * R + r] = src[(size_t)r * ld + c];
}

// ---------------------------------------------------------------------------
// scan_store: chunk-local scan (2-step fused) + inline z emission.
// grid (64 chunks, 8 batch-groups of 4), block 256.
// z[t][b][o] = xloc-part of u_t (everything except s_j M^tau Cu).
// d_j written to Sa[1+j].
// ---------------------------------------------------------------------------
__global__ void __launch_bounds__(256) scan_store_kernel(const float* __restrict__ obs,
                                                         const float* __restrict__ M2,
                                                         const float* __restrict__ PMm,
                                                         const float* __restrict__ Pm,
                                                         const float* __restrict__ TW0,
                                                         const float* __restrict__ TW1,
                                                         const float* __restrict__ TPCu,
                                                         const float* __restrict__ TDuy,
                                                         float* __restrict__ Sa,
                                                         float* __restrict__ z)
{
  __shared__ float xL[4][256];
  __shared__ float yb[2][4][128];
  const int j = blockIdx.x, bg = blockIdx.y;
  const int tid = threadIdx.x;
  const int n = tid;
  const int t0 = j * 32;
  // staging role: thread -> (t' = tid>>7, b = (tid>>5)&3, i4 = tid&31)
  const int sy_t = tid >> 7, sy_b = (tid >> 5) & 3, sy_i = tid & 31;
  const float* obs_src = obs + (size_t)(bg * 4 + sy_b) * 2048 * 128 + sy_i * 4;
  // z role: thread -> (parity zp, batch zb, out zo)  (zp wave-uniform)
  const int zp = tid >> 7, zb = (tid >> 5) & 3, zo = tid & 31;
  const int gbz = bg * 4 + zb;

  ((float*)xL)[tid] = 0.f;
  ((float*)xL)[tid + 256] = 0.f;
  ((float*)xL)[tid + 512] = 0.f;
  ((float*)xL)[tid + 768] = 0.f;
  {
    const float4 v = *reinterpret_cast<const float4*>(obs_src + (size_t)(t0 + sy_t) * 128);
    *reinterpret_cast<float4*>(&yb[sy_t][sy_b][sy_i * 4]) = v;
  }
  __syncthreads();

  float acc0, acc1, acc2, acc3;
  #pragma unroll 1
  for (int m = 0; m < 16; m++) {
    // ---- z for tau = 2m + zp ----
    float za = 0.f;
    if (zp == 0) {
      const float* tw = TW0 + zo * 256;
      #pragma unroll 4
      for (int kq = 0; kq < 64; kq++) {
        const float4 w = *reinterpret_cast<const float4*>(tw + kq * 4);
        const float4 x = *reinterpret_cast<const float4*>(&xL[zb][kq * 4]);
        za += x.x * w.x + x.y * w.y + x.z * w.z + x.w * w.w;
      }
      const float* td = TDuy + zo * 128;
      #pragma unroll 4
      for (int iq = 0; iq < 32; iq++) {
        const float4 w = *reinterpret_cast<const float4*>(td + iq * 4);
        const float4 y = *reinterpret_cast<const float4*>(&yb[0][zb][iq * 4]);
        za += y.x * w.x + y.y * w.y + y.z * w.z + y.w * w.w;
      }
    } else {
      const float* tw = TW1 + zo * 256;
      #pragma unroll 4
      for (int kq = 0; kq < 64; kq++) {
        const float4 w = *reinterpret_cast<const float4*>(tw + kq * 4);
        const float4 x = *reinterpret_cast<const float4*>(&xL[zb][kq * 4]);
        za += x.x * w.x + x.y * w.y + x.z * w.z + x.w * w.w;
      }
      const float* tp = TPCu + zo * 128;
      const float* td = TDuy + zo * 128;
      #pragma unroll 4
      for (int iq = 0; iq < 32; iq++) {
        const float4 w0 = *reinterpret_cast<const float4*>(tp + iq * 4);
        const float4 y0 = *reinterpret_cast<const float4*>(&yb[0][zb][iq * 4]);
        const float4 w1 = *reinterpret_cast<const float4*>(td + iq * 4);
        const float4 y1 = *reinterpret_cast<const float4*>(&yb[1][zb][iq * 4]);
        za += y0.x * w0.x + y0.y * w0.y + y0.z * w0.z + y0.w * w0.w;
        za += y1.x * w1.x + y1.y * w1.y + y1.z * w1.z + y1.w * w1.w;
      }
    }
    z[((size_t)(t0 + 2 * m + zp) * 32 + gbz) * 32 + zo] = za;

    // ---- x <- x M2 + y0 PM + y1 P ----
    acc0 = acc1 = acc2 = acc3 = 0.f;
    #pragma unroll 4
    for (int kq = 0; kq < 64; kq++) {
      const float* mp = M2 + (size_t)(kq * 4) * 256 + n;
      const float m0 = mp[0], m1 = mp[256], m2 = mp[512], m3 = mp[768];
      const float4 xa = *reinterpret_cast<const float4*>(&xL[0][kq * 4]);
      const float4 xb = *reinterpret_cast<const float4*>(&xL[1][kq * 4]);
      const float4 xc = *reinterpret_cast<const float4*>(&xL[2][kq * 4]);
      const float4 xd = *reinterpret_cast<const float4*>(&xL[3][kq * 4]);
      acc0 += xa.x * m0 + xa.y * m1 + xa.z * m2 + xa.w * m3;
      acc1 += xb.x * m0 + xb.y * m1 + xb.z * m2 + xb.w * m3;
      acc2 += xc.x * m0 + xc.y * m1 + xc.z * m2 + xc.w * m3;
      acc3 += xd.x * m0 + xd.y * m1 + xd.z * m2 + xd.w * m3;
    }
    #pragma unroll 4
    for (int iq = 0; iq < 32; iq++) {
      const float* pp = PMm + (size_t)(iq * 4) * 256 + n;
      const float p0 = pp[0], p1 = pp[256], p2 = pp[512], p3 = pp[768];
      const float4 ya = *reinterpret_cast<const float4*>(&yb[0][0][iq * 4]);
      const float4 yc = *reinterpret_cast<const float4*>(&yb[0][1][iq * 4]);
      const float4 ye = *reinterpret_cast<const float4*>(&yb[0][2][iq * 4]);
      const float4 yg = *reinterpret_cast<const float4*>(&yb[0][3][iq * 4]);
      acc0 += ya.x * p0 + ya.y * p1 + ya.z * p2 + ya.w * p3;
      acc1 += yc.x * p0 + yc.y * p1 + yc.z * p2 + yc.w * p3;
      acc2 += ye.x * p0 + ye.y * p1 + ye.z * p2 + ye.w * p3;
      acc3 += yg.x * p0 + yg.y * p1 + yg.z * p2 + yg.w * p3;
    }
    #pragma unroll 4
    for (int iq = 0; iq < 32; iq++) {
      const float* pp = Pm + (size_t)(iq * 4) * 256 + n;
      const float p0 = pp[0], p1 = pp[256], p2 = pp[512], p3 = pp[768];
      const float4 ya = *reinterpret_cast<const float4*>(&yb[1][0][iq * 4]);
      const float4 yc = *reinterpret_cast<const float4*>(&yb[1][1][iq * 4]);
      const float4 ye = *reinterpret_cast<const float4*>(&yb[1][2][iq * 4]);
      const float4 yg = *reinterpret_cast<const float4*>(&yb[1][3][iq * 4]);
      acc0 += ya.x * p0 + ya.y * p1 + ya.z * p2 + ya.w * p3;
      acc1 += yc.x * p0 + yc.y * p1 + yc.z * p2 + yc.w * p3;
      acc2 += ye.x * p0 + ye.y * p1 + ye.z * p2 + ye.w * p3;
      acc3 += yg.x * p0 + yg.y * p1 + yg.z * p2 + yg.w * p3;
    }
    __syncthreads();
    xL[0][n] = acc0; xL[1][n] = acc1; xL[2][n] = acc2; xL[3][n] = acc3;
    if (m < 15) {
      const float4 v = *reinterpret_cast<const float4*>(
          obs_src + (size_t)(t0 + 2 * (m + 1) + sy_t) * 128);
      *reinterpret_cast<float4*>(&yb[sy_t][sy_b][sy_i * 4]) = v;
    }
    __syncthreads();
  }
  // d_j
  float* dst = Sa + (size_t)(1 + j) * 8192 + bg * 1024;
  dst[0 * 256 + n] = acc0;
  dst[1 * 256 + n] = acc1;
  dst[2 * 256 + n] = acc2;
  dst[3 * 256 + n] = acc3;
}

// ---------------------------------------------------------------------------
// Kogge-Stone round: out[j] = in[j] + (j>=s ? in[j-s] @ W : 0)
// elements [32][256]; grid (64, 8) blocks of 256 (4 batches per block).
// ---------------------------------------------------------------------------
__global__ void __launch_bounds__(256) scan_round_kernel(const float* __restrict__ in,
                                                         float* __restrict__ out,
                                                         const float* __restrict__ W, int s)
{
  const int j = blockIdx.x, bg = blockIdx.y;
  const int n = threadIdx.x;
  const size_t eoff = (size_t)j * 8192 + bg * 1024;
  if (j < s) {
    #pragma unroll
    for (int b = 0; b < 4; b++) out[eoff + b * 256 + n] = in[eoff + b * 256 + n];
    return;
  }
  __shared__ float xL[4][256];
  const size_t soff = (size_t)(j - s) * 8192 + bg * 1024;
  #pragma unroll
  for (int b = 0; b < 4; b++) xL[b][n] = in[soff + b * 256 + n];
  __syncthreads();
  float acc0 = in[eoff + 0 * 256 + n];
  float acc1 = in[eoff + 1 * 256 + n];
  float acc2 = in[eoff + 2 * 256 + n];
  float acc3 = in[eoff + 3 * 256 + n];
  #pragma unroll 4
  for (int kq = 0; kq < 64; kq++) {
    const float* wp = W + (size_t)(kq * 4) * 256 + n;
    const float w0 = wp[0], w1 = wp[256], w2 = wp[512], w3 = wp[768];
    const float4 xa = *reinterpret_cast<const float4*>(&xL[0][kq * 4]);
    const float4 xb = *reinterpret_cast<const float4*>(&xL[1][kq * 4]);
    const float4 xc = *reinterpret_cast<const float4*>(&xL[2][kq * 4]);
    const float4 xd = *reinterpret_cast<const float4*>(&xL[3][kq * 4]);
    acc0 += xa.x * w0 + xa.y * w1 + xa.z * w2 + xa.w * w3;
    acc1 += xb.x * w0 + xb.y * w1 + xb.z * w2 + xb.w * w3;
    acc2 += xc.x * w0 + xc.y * w1 + xc.z * w2 + xc.w * w3;
    acc3 += xd.x * w0 + xd.y * w1 + xd.z * w2 + xd.w * w3;
  }
  out[eoff + 0 * 256 + n] = acc0;
  out[eoff + 1 * 256 + n] = acc1;
  out[eoff + 2 * 256 + n] = acc2;
  out[eoff + 3 * 256 + n] = acc3;
}

// ---------------------------------------------------------------------------
// uhom_emit: [2048 x 256] (S = chunk-start states, row = j*32+b) @ Wstack[256 x 1024]
// epilogue: + z, write actions and log_stds.  grid (32, 64), block 256.
// ---------------------------------------------------------------------------
__global__ void __launch_bounds__(256) uhom_emit_kernel(const float* __restrict__ S,
                                                        const float* __restrict__ W,
                                                        const float* __restrict__ z,
                                                        const float* __restrict__ logstd,
                                                        float* __restrict__ out)
{
  __shared__ float As[32][33];
  __shared__ float Bs[32][33];
  const int bx = blockIdx.x, by = blockIdx.y;
  const int tx = threadIdx.x & 31, ty = threadIdx.x >> 5;
  float acc[4] = {0.f, 0.f, 0.f, 0.f};
  for (int k0 = 0; k0 < 256; k0 += 32) {
    #pragma unroll
    for (int i = 0; i < 4; i++) {
      As[ty * 4 + i][tx] = S[(size_t)(by * 32 + ty * 4 + i) * 256 + k0 + tx];
      Bs[ty * 4 + i][tx] = W[(size_t)(k0 + ty * 4 + i) * 1024 + bx * 32 + tx];
    }
    __syncthreads();
    #pragma unroll
    for (int k = 0; k < 32; k++) {
      const float bv = Bs[k][tx];
      #pragma unroll
      for (int i = 0; i < 4; i++) acc[i] += As[ty * 4 + i][k] * bv;
    }
    __syncthreads();
  }
  const int c = bx * 32 + tx;
  const int tau = c >> 5, o = c & 31;
  const float ls = logstd[o];
  #pragma unroll
  for (int i = 0; i < 4; i++) {
    const int r = by * 32 + ty * 4 + i;
    const int jj = r >> 5, gb = r & 31;
    const int t = jj * 32 + tau;
    const float v = acc[i] + z[((size_t)t * 32 + gb) * 32 + o];
    const size_t ob = ((size_t)gb * 2048 + t) * 64;
    out[ob + o] = v;
    out[ob + 32 + o] = ls;
  }
}

// x_final = s_63 @ M^32 + d_63.  grid 32 (batch), block 256 (col n).
__global__ void __launch_bounds__(256) xf_kernel(const float* __restrict__ s63,
                                                 const float* __restrict__ d63,
                                                 const float* __restrict__ M32,
                                                 float* __restrict__ xf)
{
  __shared__ float sL[256];
  const int b = blockIdx.x, n = threadIdx.x;
  sL[n] = s63[(size_t)b * 256 + n];
  __syncthreads();
  float acc = d63[(size_t)b * 256 + n];
  #pragma unroll 4
  for (int kq = 0; kq < 64; kq++) {
    const float* mp = M32 + (size_t)(kq * 4) * 256 + n;
    const float m0 = mp[0], m1 = mp[256], m2 = mp[512], m3 = mp[768];
    const float4 s = *reinterpret_cast<const float4*>(&sL[kq * 4]);
    acc += s.x * m0 + s.y * m1 + s.z * m2 + s.w * m3;
  }
  xf[(size_t)b * 256 + n] = acc;
}

// ---------------------------------------------------------------------------
// Value MLP: thread-per-row, 64 rows per WG staged in padded LDS.
// grid 1024, block 64.
// ---------------------------------------------------------------------------
__global__ void __launch_bounds__(64) mlp_kernel(const float* __restrict__ obs,
                                                 const float* __restrict__ W0,
                                                 const float* __restrict__ b0,
                                                 const float* __restrict__ W1,
                                                 const float* __restrict__ b1,
                                                 const float* __restrict__ W2,
                                                 const float* __restrict__ b2,
                                                 float* __restrict__ val)
{
  __shared__ float oL[64][129];
  const int wg = blockIdx.x;
  const size_t base = (size_t)wg * 64 * 128;
  #pragma unroll 4
  for (int i = 0; i < 32; i++) {
    const int idx = i * 64 + threadIdx.x;  // float4 index
    const float4 v = *reinterpret_cast<const float4*>(obs + base + (size_t)idx * 4);
    const int r = idx >> 5, c4 = idx & 31;
    oL[r][c4 * 4 + 0] = v.x;
    oL[r][c4 * 4 + 1] = v.y;
    oL[r][c4 * 4 + 2] = v.z;
    oL[r][c4 * 4 + 3] = v.w;
  }
  __syncthreads();
  const int r = threadIdx.x;
  float h0[64];
  #pragma unroll
  for (int jj = 0; jj < 64; jj++) h0[jj] = b0[jj];
  #pragma unroll 2
  for (int k = 0; k < 128; k++) {
    const float x = oL[r][k];
    const float* w = W0 + (size_t)k * 64;
    #pragma unroll
    for (int jj = 0; jj < 64; jj++) h0[jj] += x * w[jj];
  }
  #pragma unroll
  for (int jj = 0; jj < 64; jj++) h0[jj] = tanhf(h0[jj]);
  float h1[64];
  #pragma unroll
  for (int jj = 0; jj < 64; jj++) h1[jj] = b1[jj];
  #pragma unroll 2
  for (int k = 0; k < 64; k++) {
    const float x = h0[k];
    const float* w = W1 + (size_t)k * 64;
    #pragma unroll
    for (int jj = 0; jj < 64; jj++) h1[jj] += x * w[jj];
  }
  float v = b2[0];
  #pragma unroll
  for (int jj = 0; jj < 64; jj++) v += tanhf(h1[jj]) * W2[jj];
  val[(size_t)wg * 64 + r] = v;
}

// ---------------------------------------------------------------------------
extern "C" void kernel_launch(void* const* d_in, const int* in_sizes, int n_in,
                              void* d_out, int out_size, void* d_ws, size_t ws_size,
                              hipStream_t stream)
{
  (void)in_sizes; (void)n_in; (void)out_size;
  if (ws_size < WS_FLOATS * sizeof(float)) return;  // fail loudly (out stays poisoned)

  const float* obs  = (const float*)d_in[0];
  const float* x0   = (const float*)d_in[1];
  const float* A_T  = (const float*)d_in[2];
  const float* ByT  = (const float*)d_in[3];
  const float* CuT  = (const float*)d_in[4];
  const float* DuyT = (const float*)d_in[5];
  const float* lstd = (const float*)d_in[6];
  const float* W0   = (const float*)d_in[7];
  const float* b0   = (const float*)d_in[8];
  const float* W1   = (const float*)d_in[9];
  const float* b1   = (const float*)d_in[10];
  const float* W2   = (const float*)d_in[11];
  const float* b2   = (const float*)d_in[12];
  float* out = (float*)d_out;
  float* ws  = (float*)d_ws;

  float* A2   = ws + OFF_A2;
  float* A3   = ws + OFF_A3;
  float* A4   = ws + OFF_A4;
  float* Pi   = ws + OFF_PI;
  float* P    = ws + OFF_P;
  float* PM   = ws + OFF_PM;
  float* PCu  = ws + OFF_PCU;
  float* W    = ws + OFF_W;
  float* TW0  = ws + OFF_TW0;
  float* TW1  = ws + OFF_TW1;
  float* TPCu = ws + OFF_TPCU;
  float* TDuy = ws + OFF_TDUY;
  float* Mp   = ws + OFF_MP;   // Mp + p*65536 = M^(2^p)
  float* Sa   = ws + OFF_SA;
  float* Sb   = ws + OFF_SB;
  float* Z    = ws + OFF_Z;

  const float h = H_DT;

  // --- A powers, M, P ---
  mm_kernel<<<dim3(8, 8), 256, 0, stream>>>(A_T, A_T, A2, 256, 256, 256, 256, 1.f);
  mm_kernel<<<dim3(8, 8), 256, 0, stream>>>(A2, A_T, A3, 256, 256, 256, 256, 1.f);
  mm_kernel<<<dim3(8, 8), 256, 0, stream>>>(A2, A2, A4, 256, 256, 256, 256, 1.f);
  ewpoly_kernel<<<256, 256, 0, stream>>>(Mp, A_T, A2, A3, A4,
                                         h, h * h / 2.f, h * h * h / 6.f, h * h * h * h / 24.f);
  ewpoly_kernel<<<256, 256, 0, stream>>>(Pi, A_T, A2, A3, A4,
                                         h / 2.f, h * h / 6.f, h * h * h / 24.f, 0.f);
  mm_kernel<<<dim3(8, 4), 256, 0, stream>>>(ByT, Pi, P, 256, 256, 256, 256, h);
  for (int p = 1; p <= 10; p++) {
    const float* src = Mp + (size_t)(p - 1) * 65536;
    mm_kernel<<<dim3(8, 8), 256, 0, stream>>>(src, src, Mp + (size_t)p * 65536,
                                              256, 256, 256, 256, 1.f);
  }
  // PM = P @ M ; PCu = P @ Cu
  mm_kernel<<<dim3(8, 4), 256, 0, stream>>>(P, Mp, PM, 256, 256, 256, 256, 1.f);
  mm_kernel<<<dim3(1, 4), 256, 0, stream>>>(P, CuT, PCu, 256, 256, 32, 32, 1.f);
  // Wstack via log-doubling: W[tau] = M^tau @ Cu, cols tau*32..tau*32+31
  copyW0_kernel<<<32, 256, 0, stream>>>(W, CuT);
  mm_kernel<<<dim3(1, 8), 256, 0, stream>>>(Mp + 0 * 65536, W, W + 32,  256, 256, 1024, 1024, 1.f);
  mm_kernel<<<dim3(2, 8), 256, 0, stream>>>(Mp + 1 * 65536, W, W + 64,  256, 256, 1024, 1024, 1.f);
  mm_kernel<<<dim3(4, 8), 256, 0, stream>>>(Mp + 2 * 65536, W, W + 128, 256, 256, 1024, 1024, 1.f);
  mm_kernel<<<dim3(8, 8), 256, 0, stream>>>(Mp + 3 * 65536, W, W + 256, 256, 256, 1024, 1024, 1.f);
  mm_kernel<<<dim3(16, 8), 256, 0, stream>>>(Mp + 4 * 65536, W, W + 512, 256, 256, 1024, 1024, 1.f);
  // transposed small panels
  transpose32_kernel<<<32, 256, 0, stream>>>(W,      TW0,  256, 1024);
  transpose32_kernel<<<32, 256, 0, stream>>>(W + 32, TW1,  256, 1024);
  transpose32_kernel<<<16, 256, 0, stream>>>(PCu,    TPCu, 128, 32);
  transpose32_kernel<<<16, 256, 0, stream>>>(DuyT,   TDuy, 128, 32);

  // --- local scans + z emission ---
  copy_kernel<<<32, 256, 0, stream>>>(Sa, x0, 8192);  // Sa[0] = x0
  scan_store_kernel<<<dim3(64, 8), 256, 0, stream>>>(obs, Mp + 65536, PM, P,
                                                     TW0, TW1, TPCu, TDuy, Sa, Z);

  // --- Kogge-Stone over 64 chunk elements (6 rounds ends back at Sa) ---
  float* cur = Sa;
  float* nxt = Sb;
  for (int r = 0; r < 6; r++) {
    scan_round_kernel<<<dim3(64, 8), 256, 0, stream>>>(cur, nxt,
                                                       Mp + (size_t)(5 + r) * 65536, 1 << r);
    float* tmp = cur; cur = nxt; nxt = tmp;
  }
  // cur == Sa: cur[j] = state at start of chunk j; Sa[64] = d_63 (untouched)

  uhom_emit_kernel<<<dim3(32, 64), 256, 0, stream>>>(cur, W, Z, lstd, out);
  xf_kernel<<<32, 256, 0, stream>>>(cur + (size_t)63 * 8192, Sa + (size_t)64 * 8192,
                                    Mp + (size_t)5 * 65536, out + OUT_XF);
  mlp_kernel<<<1024, 64, 0, stream>>>(obs, W0, b0, W1, b1, W2, b2, out + OUT_VAL);
}

// Round 3
// 649.235 us; speedup vs baseline: 3.0760x; 1.8276x over previous
//
#include <hip/hip_runtime.h>
#include <cstdint>
#include <cstddef>

// ---------------------------------------------------------------------------
// LTIModel round 3: full GEMM-ification.
//   x_{t+1} = x_t M + y_t P  (M,P = exact RK4 polynomials of A_T)
//   u_t = x_t Cu + y_t Duy
// Pipeline:
//   d8  = obs-window GEMM  [8192x1024]x[1024x256]        (8-step increments)
//   d16 = d8_even M^8 + d8_odd ; d32 -> Sa slots          (tree combine)
//   Kogge-Stone over [x0, d32_0..62] with M^(32*2^r)      (chunk starts s32)
//   s8 expand: s32 -> states every 8 steps                (4 affine launches)
//   u   = [s8 | obs-window] GEMM [8192x1280]x[1280x256]   (actions + logstd)
//   xf  = s32_63 M^32 + d32_63 ;  value MLP on obs.
// ---------------------------------------------------------------------------

static constexpr float H_DT = 0.01f;

// ws layout (floats)
static constexpr size_t OFF_MP  = 0;         // 11*65536 = 720896   Mp[p]=M^(2^p)
static constexpr size_t OFF_WS8 = 720896;    // 65536   Wstack8 [256][256] col t*32+oo = (M^t Cu)[k][oo]
static constexpr size_t OFF_BD  = 786432;    // 262144  Bd [1024][256]
static constexpr size_t OFF_BGZ = 1048576;   // 327680  BigGz [1280][256]
static constexpr size_t OFF_D8  = 1376256;   // 2097152 d8 [8192][256] rows b*256+j8
static constexpr size_t OFF_D16 = 3473408;   // 1048576 d16 [4096][256] rows b*128+j16
static constexpr size_t OFF_SA  = 4521984;   // 532480  Sa [32*65][256] rows b*65+jj
static constexpr size_t OFF_SB  = 5054464;   // 532480  Sb same layout
static constexpr size_t OFF_S8  = 5586944;   // 2097152 s8 [8192][256]  (setup scratch overlays here)
static constexpr size_t WS_FLOATS = 7684096; // 30.7 MB

// setup scratch (overlaid on s8 region; dead before s8 is written)
static constexpr size_t SC_A2   = OFF_S8 + 0;
static constexpr size_t SC_A3   = OFF_S8 + 65536;
static constexpr size_t SC_A4   = OFF_S8 + 131072;
static constexpr size_t SC_PI   = OFF_S8 + 196608;
static constexpr size_t SC_RALL = OFF_S8 + 262144;  // 8*32768: R_d = P M^d
static constexpr size_t SC_GALL = OFF_S8 + 524288;  // 8*4096:  G_d = R_d Cu

// out layout (floats)
static constexpr size_t OUT_XF  = 4194304; // 32*2048*64
static constexpr size_t OUT_VAL = 4202496; // + 32*256

// ---------------------------------------------------------------------------
// setup matmul: C = alpha * A[MxK] @ B[KxN] (row-major, leading dims).
// grid (N/32, M/32), block 256.
// ---------------------------------------------------------------------------
__global__ void __launch_bounds__(256) mm_kernel(const float* __restrict__ A,
                                                 const float* __restrict__ B,
                                                 float* __restrict__ C,
                                                 int K, int lda, int ldb, int ldc,
                                                 float alpha)
{
  __shared__ float As[32][33];
  __shared__ float Bs[32][33];
  const int bx = blockIdx.x, by = blockIdx.y;
  const int tx = threadIdx.x & 31, ty = threadIdx.x >> 5;
  float acc[4] = {0.f, 0.f, 0.f, 0.f};
  for (int k0 = 0; k0 < K; k0 += 32) {
    #pragma unroll
    for (int i = 0; i < 4; i++) {
      As[ty * 4 + i][tx] = A[(size_t)(by * 32 + ty * 4 + i) * lda + k0 + tx];
      Bs[ty * 4 + i][tx] = B[(size_t)(k0 + ty * 4 + i) * ldb + bx * 32 + tx];
    }
    __syncthreads();
    #pragma unroll
    for (int k = 0; k < 32; k++) {
      const float bv = Bs[k][tx];
      #pragma unroll
      for (int i = 0; i < 4; i++) acc[i] += As[ty * 4 + i][k] * bv;
    }
    __syncthreads();
  }
  #pragma unroll
  for (int i = 0; i < 4; i++)
    C[(size_t)(by * 32 + ty * 4 + i) * ldc + bx * 32 + tx] = alpha * acc[i];
}

__global__ void __launch_bounds__(256) ewpoly_kernel(float* __restrict__ D,
                                                     const float* __restrict__ A1,
                                                     const float* __restrict__ A2,
                                                     const float* __restrict__ A3,
                                                     const float* __restrict__ A4,
                                                     float c1, float c2, float c3, float c4)
{
  const int i = blockIdx.x * 256 + threadIdx.x;
  const int r = i >> 8, c = i & 255;
  float v = (r == c) ? 1.0f : 0.0f;
  v += c1 * A1[i] + c2 * A2[i] + c3 * A3[i] + c4 * A4[i];
  D[i] = v;
}

// Wstack8 col block 0 = CuT
__global__ void __launch_bounds__(256) seedW8_kernel(float* __restrict__ W8,
                                                     const float* __restrict__ CuT)
{
  const int idx = blockIdx.x * 256 + threadIdx.x; // 0..8191
  W8[(size_t)(idx >> 5) * 256 + (idx & 31)] = CuT[idx];
}

// Bd[(i*128+o)][n] = Rall[7-i][o][n].  grid 1024, block 256.
__global__ void __launch_bounds__(256) assembleBd_kernel(const float* __restrict__ Rall,
                                                         float* __restrict__ Bd)
{
  const int row = blockIdx.x, n = threadIdx.x;
  const int i = row >> 7, o = row & 127;
  Bd[(size_t)row * 256 + n] = Rall[(size_t)(7 - i) * 32768 + o * 256 + n];
}

// BigGz [1280][256]: rows<256 = Wstack8; rows 256+(i*128+o), col tau*32+oo:
//   i<tau -> Gall[tau-1-i][o][oo]; i==tau -> DuyT[o][oo]; else 0.
__global__ void __launch_bounds__(256) assembleBGZ_kernel(const float* __restrict__ W8,
                                                          const float* __restrict__ Gall,
                                                          const float* __restrict__ DuyT,
                                                          float* __restrict__ BGZ)
{
  const int row = blockIdx.x, c = threadIdx.x;
  float v;
  if (row < 256) {
    v = W8[(size_t)row * 256 + c];
  } else {
    const int ri = row - 256;
    const int i = ri >> 7, o = ri & 127;
    const int tau = c >> 5, oo = c & 31;
    if (i < tau)       v = Gall[(size_t)(tau - 1 - i) * 4096 + o * 32 + oo];
    else if (i == tau) v = DuyT[o * 32 + oo];
    else               v = 0.f;
  }
  BGZ[(size_t)row * 256 + c] = v;
}

// Sa[b*65+0] = x0[b].  grid 32, block 256.
__global__ void __launch_bounds__(256) seedS_kernel(const float* __restrict__ x0,
                                                    float* __restrict__ Sa)
{
  const int b = blockIdx.x, n = threadIdx.x;
  Sa[(size_t)(b * 65) * 256 + n] = x0[(size_t)b * 256 + n];
}

// s8[b*256+4j] = Sa[b*65+j].  grid 2048, block 256.
__global__ void __launch_bounds__(256) copyS0_kernel(const float* __restrict__ S,
                                                     float* __restrict__ s8)
{
  const int p = blockIdx.x, n = threadIdx.x;
  const int b = p >> 6, j = p & 63;
  s8[(size_t)(b * 256 + 4 * j) * 256 + n] = S[(size_t)(b * 65 + j) * 256 + n];
}

// ---------------------------------------------------------------------------
// affine: Y[b*yC + j*ymul + yadd] = X[b*xC + j*xmul + xadd] @ W + D[b*dC + j*dmul + dadd]
// 8 output (b,j) pairs per block; thread = column n. grid = 32*jcount/8.
// ---------------------------------------------------------------------------
__global__ void __launch_bounds__(256) affine_kernel(const float* __restrict__ X,
                                                     const float* __restrict__ W,
                                                     const float* __restrict__ D,
                                                     float* __restrict__ Y,
                                                     int jshift, int xC, int xmul, int xadd,
                                                     int dC, int dmul, int dadd,
                                                     int yC, int ymul, int yadd)
{
  __shared__ float xL[8][256];
  const int n = threadIdx.x;
  const int p0 = blockIdx.x * 8;
  const int jmask = (1 << jshift) - 1;
  int xrow[8], drow[8], yrow[8];
  #pragma unroll
  for (int q = 0; q < 8; q++) {
    const int p = p0 + q;
    const int b = p >> jshift, j = p & jmask;
    xrow[q] = b * xC + j * xmul + xadd;
    drow[q] = b * dC + j * dmul + dadd;
    yrow[q] = b * yC + j * ymul + yadd;
  }
  #pragma unroll
  for (int q = 0; q < 8; q++) xL[q][n] = X[(size_t)xrow[q] * 256 + n];
  __syncthreads();
  float acc[8];
  #pragma unroll
  for (int q = 0; q < 8; q++) acc[q] = D[(size_t)drow[q] * 256 + n];
  #pragma unroll 2
  for (int kq = 0; kq < 64; kq++) {
    const float* wp = W + (size_t)(kq * 4) * 256 + n;
    const float w0 = wp[0], w1 = wp[256], w2 = wp[512], w3 = wp[768];
    #pragma unroll
    for (int q = 0; q < 8; q++) {
      const float4 x = *reinterpret_cast<const float4*>(&xL[q][kq * 4]);
      acc[q] += x.x * w0 + x.y * w1 + x.z * w2 + x.w * w3;
    }
  }
  #pragma unroll
  for (int q = 0; q < 8; q++) Y[(size_t)yrow[q] * 256 + n] = acc[q];
}

// ---------------------------------------------------------------------------
// Kogge-Stone round over (b, jj<64) pairs stored at rows b*65+jj.
// out[jj] = in[jj] + (jj>=s ? in[jj-s] @ W : 0).  8 pairs/block, grid 256.
// ---------------------------------------------------------------------------
__global__ void __launch_bounds__(256) ks_kernel(const float* __restrict__ in,
                                                 float* __restrict__ out,
                                                 const float* __restrict__ W, int s)
{
  __shared__ float xL[8][256];
  const int n = threadIdx.x;
  const int p0 = blockIdx.x * 8;
  int erow[8];
  #pragma unroll
  for (int q = 0; q < 8; q++) {
    const int p = p0 + q;
    const int b = p >> 6, jj = p & 63;
    erow[q] = b * 65 + jj;
    const bool valid = jj >= s;
    xL[q][n] = valid ? in[(size_t)(erow[q] - s) * 256 + n] : 0.f;
  }
  __syncthreads();
  float acc[8];
  #pragma unroll
  for (int q = 0; q < 8; q++) acc[q] = in[(size_t)erow[q] * 256 + n];
  #pragma unroll 2
  for (int kq = 0; kq < 64; kq++) {
    const float* wp = W + (size_t)(kq * 4) * 256 + n;
    const float w0 = wp[0], w1 = wp[256], w2 = wp[512], w3 = wp[768];
    #pragma unroll
    for (int q = 0; q < 8; q++) {
      const float4 x = *reinterpret_cast<const float4*>(&xL[q][kq * 4]);
      acc[q] += x.x * w0 + x.y * w1 + x.z * w2 + x.w * w3;
    }
  }
  #pragma unroll
  for (int q = 0; q < 8; q++) out[(size_t)erow[q] * 256 + n] = acc[q];
}

// ---------------------------------------------------------------------------
// gemm_d8: d8[8192x256] = A_obs[8192x1024] @ Bd[1024x256].
// A[r][k] = obs[(r>>8)*262144 + (r&255)*1024 + k].
// 64x64 tiles, BK=16, block 256 (16x16), software prefetch.
// grid (128, 4).
// ---------------------------------------------------------------------------
__global__ void __launch_bounds__(256) gemm_d8_kernel(const float* __restrict__ obs,
                                                      const float* __restrict__ Bd,
                                                      float* __restrict__ d8)
{
  __shared__ float As[16][68];
  __shared__ float Bs[16][64];
  const int tid = threadIdx.x;
  const int tx = tid & 15, ty = tid >> 4;
  const int row0 = blockIdx.x * 64, col0 = blockIdx.y * 64;
  const int arow = tid >> 2, ak4 = tid & 3;
  const int bk = tid >> 4, bc4 = tid & 15;
  const int r = row0 + arow;
  const size_t abase = (size_t)(r >> 8) * 262144 + (size_t)(r & 255) * 1024;

  float acc[4][4];
  #pragma unroll
  for (int i = 0; i < 4; i++)
    #pragma unroll
    for (int q = 0; q < 4; q++) acc[i][q] = 0.f;

  float4 av = *reinterpret_cast<const float4*>(obs + abase + ak4 * 4);
  float4 bv = *reinterpret_cast<const float4*>(Bd + (size_t)bk * 256 + col0 + bc4 * 4);

  for (int kt = 0; kt < 64; kt++) {
    As[ak4 * 4 + 0][arow] = av.x;
    As[ak4 * 4 + 1][arow] = av.y;
    As[ak4 * 4 + 2][arow] = av.z;
    As[ak4 * 4 + 3][arow] = av.w;
    *reinterpret_cast<float4*>(&Bs[bk][bc4 * 4]) = bv;
    __syncthreads();
    if (kt < 63) {
      const int gk = (kt + 1) * 16;
      av = *reinterpret_cast<const float4*>(obs + abase + gk + ak4 * 4);
      bv = *reinterpret_cast<const float4*>(Bd + (size_t)(gk + bk) * 256 + col0 + bc4 * 4);
    }
    #pragma unroll
    for (int kk = 0; kk < 16; kk++) {
      const float4 a = *reinterpret_cast<const float4*>(&As[kk][ty * 4]);
      const float4 b = *reinterpret_cast<const float4*>(&Bs[kk][tx * 4]);
      acc[0][0] += a.x * b.x; acc[0][1] += a.x * b.y; acc[0][2] += a.x * b.z; acc[0][3] += a.x * b.w;
      acc[1][0] += a.y * b.x; acc[1][1] += a.y * b.y; acc[1][2] += a.y * b.z; acc[1][3] += a.y * b.w;
      acc[2][0] += a.z * b.x; acc[2][1] += a.z * b.y; acc[2][2] += a.z * b.z; acc[2][3] += a.z * b.w;
      acc[3][0] += a.w * b.x; acc[3][1] += a.w * b.y; acc[3][2] += a.w * b.z; acc[3][3] += a.w * b.w;
    }
    __syncthreads();
  }
  #pragma unroll
  for (int i = 0; i < 4; i++) {
    float4 st = make_float4(acc[i][0], acc[i][1], acc[i][2], acc[i][3]);
    *reinterpret_cast<float4*>(d8 + (size_t)(row0 + ty * 4 + i) * 256 + col0 + tx * 4) = st;
  }
}

// ---------------------------------------------------------------------------
// gemm_uhom: U[8192x256] = [s8 | obs-window][8192x1280] @ BigGz[1280x256],
// epilogue writes actions + log_stds.  grid (128, 4).
// ---------------------------------------------------------------------------
__global__ void __launch_bounds__(256) gemm_uhom_kernel(const float* __restrict__ s8,
                                                        const float* __restrict__ obs,
                                                        const float* __restrict__ BGZ,
                                                        const float* __restrict__ logstd,
                                                        float* __restrict__ out)
{
  __shared__ float As[16][68];
  __shared__ float Bs[16][64];
  const int tid = threadIdx.x;
  const int tx = tid & 15, ty = tid >> 4;
  const int row0 = blockIdx.x * 64, col0 = blockIdx.y * 64;
  const int arow = tid >> 2, ak4 = tid & 3;
  const int bk = tid >> 4, bc4 = tid & 15;
  const int r = row0 + arow;
  const size_t obase = (size_t)(r >> 8) * 262144 + (size_t)(r & 255) * 1024;
  const size_t sbase = (size_t)r * 256;

  float acc[4][4];
  #pragma unroll
  for (int i = 0; i < 4; i++)
    #pragma unroll
    for (int q = 0; q < 4; q++) acc[i][q] = 0.f;

  float4 av = *reinterpret_cast<const float4*>(s8 + sbase + ak4 * 4);
  float4 bv = *reinterpret_cast<const float4*>(BGZ + (size_t)bk * 256 + col0 + bc4 * 4);

  for (int kt = 0; kt < 80; kt++) {
    As[ak4 * 4 + 0][arow] = av.x;
    As[ak4 * 4 + 1][arow] = av.y;
    As[ak4 * 4 + 2][arow] = av.z;
    As[ak4 * 4 + 3][arow] = av.w;
    *reinterpret_cast<float4*>(&Bs[bk][bc4 * 4]) = bv;
    __syncthreads();
    if (kt < 79) {
      const int gk = (kt + 1) * 16;
      if (gk < 256)
        av = *reinterpret_cast<const float4*>(s8 + sbase + gk + ak4 * 4);
      else
        av = *reinterpret_cast<const float4*>(obs + obase + (gk - 256) + ak4 * 4);
      bv = *reinterpret_cast<const float4*>(BGZ + (size_t)(gk + bk) * 256 + col0 + bc4 * 4);
    }
    #pragma unroll
    for (int kk = 0; kk < 16; kk++) {
      const float4 a = *reinterpret_cast<const float4*>(&As[kk][ty * 4]);
      const float4 b = *reinterpret_cast<const float4*>(&Bs[kk][tx * 4]);
      acc[0][0] += a.x * b.x; acc[0][1] += a.x * b.y; acc[0][2] += a.x * b.z; acc[0][3] += a.x * b.w;
      acc[1][0] += a.y * b.x; acc[1][1] += a.y * b.y; acc[1][2] += a.y * b.z; acc[1][3] += a.y * b.w;
      acc[2][0] += a.z * b.x; acc[2][1] += a.z * b.y; acc[2][2] += a.z * b.z; acc[2][3] += a.z * b.w;
      acc[3][0] += a.w * b.x; acc[3][1] += a.w * b.y; acc[3][2] += a.w * b.z; acc[3][3] += a.w * b.w;
    }
    __syncthreads();
  }
  // epilogue: col c -> (tau, oo); t = j8*8+tau
  float ls[4];
  #pragma unroll
  for (int q = 0; q < 4; q++) ls[q] = logstd[(col0 + tx * 4 + q) & 31];
  #pragma unroll
  for (int i = 0; i < 4; i++) {
    const int rr = row0 + ty * 4 + i;
    const int b = rr >> 8, j8 = rr & 255;
    #pragma unroll
    for (int q = 0; q < 4; q++) {
      const int c = col0 + tx * 4 + q;
      const int tau = c >> 5, oo = c & 31;
      const size_t ob = ((size_t)b * 2048 + j8 * 8 + tau) * 64;
      out[ob + oo] = acc[i][q];
      out[ob + 32 + oo] = ls[q];
    }
  }
}

// x_final = Sa[b*65+63] @ M^32 + Sa[b*65+64].  grid 32, block 256.
__global__ void __launch_bounds__(256) xf_kernel(const float* __restrict__ S,
                                                 const float* __restrict__ M32,
                                                 float* __restrict__ xf)
{
  __shared__ float sL[256];
  const int b = blockIdx.x, n = threadIdx.x;
  sL[n] = S[(size_t)(b * 65 + 63) * 256 + n];
  __syncthreads();
  float acc = S[(size_t)(b * 65 + 64) * 256 + n];
  #pragma unroll 4
  for (int kq = 0; kq < 64; kq++) {
    const float* mp = M32 + (size_t)(kq * 4) * 256 + n;
    const float m0 = mp[0], m1 = mp[256], m2 = mp[512], m3 = mp[768];
    const float4 s = *reinterpret_cast<const float4*>(&sL[kq * 4]);
    acc += s.x * m0 + s.y * m1 + s.z * m2 + s.w * m3;
  }
  xf[(size_t)b * 256 + n] = acc;
}

// ---------------------------------------------------------------------------
// Value MLP: thread-per-row, 64 rows per WG.  grid 1024, block 64.
// ---------------------------------------------------------------------------
__global__ void __launch_bounds__(64) mlp_kernel(const float* __restrict__ obs,
                                                 const float* __restrict__ W0,
                                                 const float* __restrict__ b0,
                                                 const float* __restrict__ W1,
                                                 const float* __restrict__ b1,
                                                 const float* __restrict__ W2,
                                                 const float* __restrict__ b2,
                                                 float* __restrict__ val)
{
  __shared__ float oL[64][129];
  const int wg = blockIdx.x;
  const size_t base = (size_t)wg * 64 * 128;
  #pragma unroll 4
  for (int i = 0; i < 32; i++) {
    const int idx = i * 64 + threadIdx.x;
    const float4 v = *reinterpret_cast<const float4*>(obs + base + (size_t)idx * 4);
    const int r = idx >> 5, c4 = idx & 31;
    oL[r][c4 * 4 + 0] = v.x;
    oL[r][c4 * 4 + 1] = v.y;
    oL[r][c4 * 4 + 2] = v.z;
    oL[r][c4 * 4 + 3] = v.w;
  }
  __syncthreads();
  const int rr = threadIdx.x;
  float h0[64];
  #pragma unroll
  for (int jj = 0; jj < 64; jj++) h0[jj] = b0[jj];
  #pragma unroll 2
  for (int k = 0; k < 128; k++) {
    const float x = oL[rr][k];
    const float* w = W0 + (size_t)k * 64;
    #pragma unroll
    for (int jj = 0; jj < 64; jj++) h0[jj] += x * w[jj];
  }
  #pragma unroll
  for (int jj = 0; jj < 64; jj++) h0[jj] = tanhf(h0[jj]);
  float h1[64];
  #pragma unroll
  for (int jj = 0; jj < 64; jj++) h1[jj] = b1[jj];
  #pragma unroll 2
  for (int k = 0; k < 64; k++) {
    const float x = h0[k];
    const float* w = W1 + (size_t)k * 64;
    #pragma unroll
    for (int jj = 0; jj < 64; jj++) h1[jj] += x * w[jj];
  }
  float v = b2[0];
  #pragma unroll
  for (int jj = 0; jj < 64; jj++) v += tanhf(h1[jj]) * W2[jj];
  val[(size_t)wg * 64 + rr] = v;
}

// ---------------------------------------------------------------------------
extern "C" void kernel_launch(void* const* d_in, const int* in_sizes, int n_in,
                              void* d_out, int out_size, void* d_ws, size_t ws_size,
                              hipStream_t stream)
{
  (void)in_sizes; (void)n_in; (void)out_size;
  if (ws_size < WS_FLOATS * sizeof(float)) return;  // fail loudly (out stays poisoned)

  const float* obs  = (const float*)d_in[0];
  const float* x0   = (const float*)d_in[1];
  const float* A_T  = (const float*)d_in[2];
  const float* ByT  = (const float*)d_in[3];
  const float* CuT  = (const float*)d_in[4];
  const float* DuyT = (const float*)d_in[5];
  const float* lstd = (const float*)d_in[6];
  const float* W0   = (const float*)d_in[7];
  const float* b0   = (const float*)d_in[8];
  const float* W1   = (const float*)d_in[9];
  const float* b1   = (const float*)d_in[10];
  const float* W2   = (const float*)d_in[11];
  const float* b2   = (const float*)d_in[12];
  float* out = (float*)d_out;
  float* ws  = (float*)d_ws;

  float* Mp   = ws + OFF_MP;
  float* W8   = ws + OFF_WS8;
  float* Bd   = ws + OFF_BD;
  float* BGZ  = ws + OFF_BGZ;
  float* d8   = ws + OFF_D8;
  float* d16  = ws + OFF_D16;
  float* Sa   = ws + OFF_SA;
  float* Sb   = ws + OFF_SB;
  float* s8   = ws + OFF_S8;
  float* A2   = ws + SC_A2;
  float* A3   = ws + SC_A3;
  float* A4   = ws + SC_A4;
  float* Pi   = ws + SC_PI;
  float* Rall = ws + SC_RALL;
  float* Gall = ws + SC_GALL;

  const float h = H_DT;

  // --- setup: M, P, powers, panels ---
  mm_kernel<<<dim3(8, 8), 256, 0, stream>>>(A_T, A_T, A2, 256, 256, 256, 256, 1.f);
  mm_kernel<<<dim3(8, 8), 256, 0, stream>>>(A2, A_T, A3, 256, 256, 256, 256, 1.f);
  mm_kernel<<<dim3(8, 8), 256, 0, stream>>>(A2, A2, A4, 256, 256, 256, 256, 1.f);
  ewpoly_kernel<<<256, 256, 0, stream>>>(Mp, A_T, A2, A3, A4,
                                         h, h * h / 2.f, h * h * h / 6.f, h * h * h * h / 24.f);
  ewpoly_kernel<<<256, 256, 0, stream>>>(Pi, A_T, A2, A3, A4,
                                         h / 2.f, h * h / 6.f, h * h * h / 24.f, 0.f);
  // R0 = P = h * ByT @ Pi
  mm_kernel<<<dim3(8, 4), 256, 0, stream>>>(ByT, Pi, Rall, 256, 256, 256, 256, h);
  for (int p = 1; p <= 10; p++) {
    const float* src = Mp + (size_t)(p - 1) * 65536;
    mm_kernel<<<dim3(8, 8), 256, 0, stream>>>(src, src, Mp + (size_t)p * 65536,
                                              256, 256, 256, 256, 1.f);
  }
  // R doubling: R1 = R0 M ; R[2:4) = R[0:2) M^2 ; R[4:8) = R[0:4) M^4
  mm_kernel<<<dim3(8, 4), 256, 0, stream>>>(Rall, Mp, Rall + 32768, 256, 256, 256, 256, 1.f);
  mm_kernel<<<dim3(8, 8), 256, 0, stream>>>(Rall, Mp + 65536, Rall + 65536, 256, 256, 256, 256, 1.f);
  mm_kernel<<<dim3(8, 16), 256, 0, stream>>>(Rall, Mp + 131072, Rall + 131072, 256, 256, 256, 256, 1.f);
  // Gall = Rall[1024x256] @ CuT[256x32]
  mm_kernel<<<dim3(1, 32), 256, 0, stream>>>(Rall, CuT, Gall, 256, 256, 32, 32, 1.f);
  // Wstack8 via doubling
  seedW8_kernel<<<32, 256, 0, stream>>>(W8, CuT);
  mm_kernel<<<dim3(1, 8), 256, 0, stream>>>(Mp, W8, W8 + 32, 256, 256, 256, 256, 1.f);
  mm_kernel<<<dim3(2, 8), 256, 0, stream>>>(Mp + 65536, W8, W8 + 64, 256, 256, 256, 256, 1.f);
  mm_kernel<<<dim3(4, 8), 256, 0, stream>>>(Mp + 131072, W8, W8 + 128, 256, 256, 256, 256, 1.f);
  assembleBd_kernel<<<1024, 256, 0, stream>>>(Rall, Bd);
  assembleBGZ_kernel<<<1280, 256, 0, stream>>>(W8, Gall, DuyT, BGZ);

  // --- main pipeline ---
  gemm_d8_kernel<<<dim3(128, 4), 256, 0, stream>>>(obs, Bd, d8);
  seedS_kernel<<<32, 256, 0, stream>>>(x0, Sa);
  // d16 = d8_even M^8 + d8_odd
  affine_kernel<<<512, 256, 0, stream>>>(d8, Mp + 3 * 65536, d8, d16,
                                         7, 256, 2, 0, 256, 2, 1, 128, 1, 0);
  // Sa[jj+1] = d32_j = d16_even M^16 + d16_odd
  affine_kernel<<<256, 256, 0, stream>>>(d16, Mp + 4 * 65536, d16, Sa,
                                         6, 128, 2, 0, 128, 2, 1, 65, 1, 1);
  // Kogge-Stone (ends back in Sa after 6 rounds)
  float* cur = Sa;
  float* nxt = Sb;
  for (int rr = 0; rr < 6; rr++) {
    ks_kernel<<<256, 256, 0, stream>>>(cur, nxt, Mp + (size_t)(5 + rr) * 65536, 1 << rr);
    float* tmp = cur; cur = nxt; nxt = tmp;
  }
  // expand: s8 at 8-step grid
  copyS0_kernel<<<2048, 256, 0, stream>>>(cur, s8);
  affine_kernel<<<256, 256, 0, stream>>>(cur, Mp + 3 * 65536, d8, s8,
                                         6, 65, 1, 0, 256, 4, 0, 256, 4, 1);
  affine_kernel<<<256, 256, 0, stream>>>(cur, Mp + 4 * 65536, d16, s8,
                                         6, 65, 1, 0, 128, 2, 0, 256, 4, 2);
  affine_kernel<<<256, 256, 0, stream>>>(s8, Mp + 3 * 65536, d8, s8,
                                         6, 256, 4, 2, 256, 4, 2, 256, 4, 3);
  // actions
  gemm_uhom_kernel<<<dim3(128, 4), 256, 0, stream>>>(s8, obs, BGZ, lstd, out);
  xf_kernel<<<32, 256, 0, stream>>>(cur, Mp + 5 * 65536, out + OUT_XF);
  mlp_kernel<<<1024, 64, 0, stream>>>(obs, W0, b0, W1, b1, W2, b2, out + OUT_VAL);
}